// Round 2
// baseline (1071.419 us; speedup 1.0000x reference)
//
#include <hip/hip_runtime.h>

#define BB 2048
#define TT 512
#define INDIM 6
#define HH 32
#define OUTD 64

// single v_rcp_f32 (1 ulp) instead of the exact-divide sequence
__device__ __forceinline__ float sigm(float x) {
    return __builtin_amdgcn_rcpf(1.f + __expf(-x));
}

__global__ __launch_bounds__(64, 1) void lstm2_fused_kernel(
    const float* __restrict__ imu,
    const float* __restrict__ w_ih0, const float* __restrict__ w_hh0,
    const float* __restrict__ b_ih0, const float* __restrict__ b_hh0,
    const float* __restrict__ w_ih1, const float* __restrict__ w_hh1,
    const float* __restrict__ b_ih1, const float* __restrict__ b_hh1,
    const float* __restrict__ wf, const float* __restrict__ bf,
    const float* __restrict__ wn, const float* __restrict__ bn,
    float* __restrict__ out)
{
    const int b = blockIdx.x;
    const int lane = threadIdx.x;

    __shared__ __align__(16) float simu[TT * INDIM];
    __shared__ __align__(16) float hb1[HH];
    __shared__ __align__(16) float hb2[HH];

    // ---- stage this batch's imu sequence into LDS (3072 floats = 768 float4)
    {
        const float4* gi4 = (const float4*)(imu + (size_t)b * TT * INDIM);
        float4* si4 = (float4*)simu;
        #pragma unroll
        for (int i = 0; i < (TT * INDIM / 4) / 64; ++i)
            si4[lane + 64 * i] = gi4[lane + 64 * i];
    }

    // ---- per-lane gate ownership: gates gA=lane, gB=lane+64
    // gate index semantics: [0..31]=i, [32..63]=f, [64..95]=g, [96..127]=o
    const int gA = lane;
    const int gB = lane + 64;

    float wA0[INDIM], wB0[INDIM];
    #pragma unroll
    for (int i = 0; i < INDIM; ++i) {
        wA0[i] = w_ih0[gA * INDIM + i];
        wB0[i] = w_ih0[gB * INDIM + i];
    }
    float4 wA1[8], wB1[8], wA2i[8], wA2h[8], wB2i[8], wB2h[8];
    {
        const float4* wh0 = (const float4*)w_hh0;
        const float4* wi1 = (const float4*)w_ih1;
        const float4* wh1 = (const float4*)w_hh1;
        #pragma unroll
        for (int k = 0; k < 8; ++k) {
            wA1[k]  = wh0[gA * 8 + k];
            wB1[k]  = wh0[gB * 8 + k];
            wA2i[k] = wi1[gA * 8 + k];
            wB2i[k] = wi1[gB * 8 + k];
            wA2h[k] = wh1[gA * 8 + k];
            wB2h[k] = wh1[gB * 8 + k];
        }
    }
    const float bA1 = b_ih0[gA] + b_hh0[gA];
    const float bB1 = b_ih0[gB] + b_hh0[gB];
    const float bA2 = b_ih1[gA] + b_hh1[gA];
    const float bB2 = b_ih1[gB] + b_hh1[gB];

    hb1[lane & 31] = 0.f;
    hb2[lane & 31] = 0.f;
    float c1 = 0.f, c2 = 0.f;
    __syncthreads();   // once: simu + h init visible; in-loop ordering relies on
                       // single-wave in-order DS + same-object alias ordering

    const bool lo = (lane < 32);
    const float4* h1v = (const float4*)hb1;
    const float4* h2v = (const float4*)hb2;

    for (int t = 0; t < TT; ++t) {
        // ================= layer 1 =================
        float aA0 = bA1, aA1 = 0.f, aB0 = bB1, aB1 = 0.f;
        {
            const float* xt = simu + t * INDIM;
            float2 x01 = *(const float2*)(xt);
            float2 x23 = *(const float2*)(xt + 2);
            float2 x45 = *(const float2*)(xt + 4);
            aA0 += wA0[0] * x01.x + wA0[2] * x23.x + wA0[4] * x45.x;
            aA1 += wA0[1] * x01.y + wA0[3] * x23.y + wA0[5] * x45.y;
            aB0 += wB0[0] * x01.x + wB0[2] * x23.x + wB0[4] * x45.x;
            aB1 += wB0[1] * x01.y + wB0[3] * x23.y + wB0[5] * x45.y;
        }
        #pragma unroll
        for (int k = 0; k < 8; k += 2) {
            float4 hv0 = h1v[k];
            float4 hv1 = h1v[k + 1];
            aA0 += wA1[k].x * hv0.x + wA1[k].y * hv0.y + wA1[k].z * hv0.z + wA1[k].w * hv0.w;
            aA1 += wA1[k+1].x * hv1.x + wA1[k+1].y * hv1.y + wA1[k+1].z * hv1.z + wA1[k+1].w * hv1.w;
            aB0 += wB1[k].x * hv0.x + wB1[k].y * hv0.y + wB1[k].z * hv0.z + wB1[k].w * hv0.w;
            aB1 += wB1[k+1].x * hv1.x + wB1[k+1].y * hv1.y + wB1[k+1].z * hv1.z + wB1[k+1].w * hv1.w;
        }
        float accA = aA0 + aA1;
        float accB = aB0 + aB1;
        // activation before exchange: accA is i (lo) or f (hi) -> sigmoid.
        // accB is g (lo, tanh) or o (hi, sigmoid). tanh(x) = 2*sigm(2x)-1.
        float sA = sigm(accA);
        float sB = sigm(lo ? 2.f * accB : accB);
        float aB = lo ? 2.f * sB - 1.f : sB;
        float oA = __shfl_xor(sA, 32);
        float oB = __shfl_xor(aB, 32);
        float ig = lo ? sA : oA;
        float fg = lo ? oA : sA;
        float gg = lo ? aB : oB;
        float og = lo ? oB : aB;
        c1 = fg * c1 + ig * gg;
        float th1 = 2.f * sigm(2.f * c1) - 1.f;
        float h1n = og * th1;
        hb1[lane & 31] = h1n;   // pair lanes write identical value

        // ================= layer 2 =================
        float a2A0 = bA2, a2A1 = 0.f, a2B0 = bB2, a2B1 = 0.f;
        #pragma unroll
        for (int k = 0; k < 8; k += 2) {
            float4 av0 = h1v[k];
            float4 av1 = h1v[k + 1];
            float4 bv0 = h2v[k];
            float4 bv1 = h2v[k + 1];
            a2A0 += wA2i[k].x * av0.x + wA2i[k].y * av0.y + wA2i[k].z * av0.z + wA2i[k].w * av0.w;
            a2A1 += wA2i[k+1].x * av1.x + wA2i[k+1].y * av1.y + wA2i[k+1].z * av1.z + wA2i[k+1].w * av1.w;
            a2A0 += wA2h[k].x * bv0.x + wA2h[k].y * bv0.y + wA2h[k].z * bv0.z + wA2h[k].w * bv0.w;
            a2A1 += wA2h[k+1].x * bv1.x + wA2h[k+1].y * bv1.y + wA2h[k+1].z * bv1.z + wA2h[k+1].w * bv1.w;
            a2B0 += wB2i[k].x * av0.x + wB2i[k].y * av0.y + wB2i[k].z * av0.z + wB2i[k].w * av0.w;
            a2B1 += wB2i[k+1].x * av1.x + wB2i[k+1].y * av1.y + wB2i[k+1].z * av1.z + wB2i[k+1].w * av1.w;
            a2B0 += wB2h[k].x * bv0.x + wB2h[k].y * bv0.y + wB2h[k].z * bv0.z + wB2h[k].w * bv0.w;
            a2B1 += wB2h[k+1].x * bv1.x + wB2h[k+1].y * bv1.y + wB2h[k+1].z * bv1.z + wB2h[k+1].w * bv1.w;
        }
        float accA2 = a2A0 + a2A1;
        float accB2 = a2B0 + a2B1;
        float sA2 = sigm(accA2);
        float sB2 = sigm(lo ? 2.f * accB2 : accB2);
        float aB2 = lo ? 2.f * sB2 - 1.f : sB2;
        float oA2 = __shfl_xor(sA2, 32);
        float oB2 = __shfl_xor(aB2, 32);
        float ig2 = lo ? sA2 : oA2;
        float fg2 = lo ? oA2 : sA2;
        float gg2 = lo ? aB2 : oB2;
        float og2 = lo ? oB2 : aB2;
        c2 = fg2 * c2 + ig2 * gg2;
        float th2 = 2.f * sigm(2.f * c2) - 1.f;
        float h2n = og2 * th2;
        hb2[lane & 31] = h2n;
    }

    // ================= heads =================
    float accF = bf[lane];
    float accN = bn[lane];
    {
        const float4* wf4 = (const float4*)(wf + lane * HH);
        const float4* wn4 = (const float4*)(wn + lane * HH);
        #pragma unroll
        for (int k = 0; k < 8; ++k) {
            float4 hv = h2v[k];
            float4 f4 = wf4[k];
            float4 n4 = wn4[k];
            accF += f4.x * hv.x + f4.y * hv.y + f4.z * hv.z + f4.w * hv.w;
            accN += n4.x * hv.x + n4.y * hv.y + n4.z * hv.z + n4.w * hv.w;
        }
    }
    out[(size_t)b * OUTD + lane] = accF;
    out[(size_t)BB * OUTD + (size_t)b * OUTD + lane] = __expf(accN);
}

extern "C" void kernel_launch(void* const* d_in, const int* in_sizes, int n_in,
                              void* d_out, int out_size, void* d_ws, size_t ws_size,
                              hipStream_t stream) {
    const float* imu   = (const float*)d_in[0];
    const float* w_ih0 = (const float*)d_in[1];
    const float* w_hh0 = (const float*)d_in[2];
    const float* b_ih0 = (const float*)d_in[3];
    const float* b_hh0 = (const float*)d_in[4];
    const float* w_ih1 = (const float*)d_in[5];
    const float* w_hh1 = (const float*)d_in[6];
    const float* b_ih1 = (const float*)d_in[7];
    const float* b_hh1 = (const float*)d_in[8];
    const float* wf    = (const float*)d_in[9];
    const float* bf    = (const float*)d_in[10];
    const float* wn    = (const float*)d_in[11];
    const float* bn    = (const float*)d_in[12];
    float* out = (float*)d_out;

    lstm2_fused_kernel<<<dim3(BB), dim3(64), 0, stream>>>(
        imu, w_ih0, w_hh0, b_ih0, b_hh0,
        w_ih1, w_hh1, b_ih1, b_hh1,
        wf, bf, wn, bn, out);
}

// Round 3
// 490.679 us; speedup vs baseline: 2.1835x; 2.1835x over previous
//
#include <hip/hip_runtime.h>

#define TT 512
#define BPB 8                 // batches per block
#define NBLK (2048 / BPB)     // 256 blocks = 1 per CU
#define OUTD 64

typedef __attribute__((ext_vector_type(8))) short short8;
typedef __attribute__((ext_vector_type(4))) float f32x4;

__device__ __forceinline__ short f2bf(float x) {  // RNE float->bf16
    union { float f; unsigned u; } v; v.f = x;
    unsigned r = (v.u + 0x7FFFu + ((v.u >> 16) & 1u)) >> 16;
    return (short)r;
}
__device__ __forceinline__ float sigm(float x) {
    return __builtin_amdgcn_rcpf(1.f + __expf(-x));
}
__device__ __forceinline__ float tanh_fast(float x) {
    return 2.f * sigm(2.f * x) - 1.f;
}

// B-fragment for 16x16x32 bf16: lane holds B[k][col], col=l&15, k=kg*8+j
__device__ __forceinline__ short8 load_bfrag(const float* __restrict__ W, int G, int kg) {
    const float4 f0 = *(const float4*)(W + G * 32 + kg * 8);
    const float4 f1 = *(const float4*)(W + G * 32 + kg * 8 + 4);
    short8 r;
    r[0] = f2bf(f0.x); r[1] = f2bf(f0.y); r[2] = f2bf(f0.z); r[3] = f2bf(f0.w);
    r[4] = f2bf(f1.x); r[5] = f2bf(f1.y); r[6] = f2bf(f1.z); r[7] = f2bf(f1.w);
    return r;
}

__global__ __launch_bounds__(256, 1) void lstm2_mfma_kernel(
    const float* __restrict__ imu,
    const float* __restrict__ w_ih0, const float* __restrict__ w_hh0,
    const float* __restrict__ b_ih0, const float* __restrict__ b_hh0,
    const float* __restrict__ w_ih1, const float* __restrict__ w_hh1,
    const float* __restrict__ b_ih1, const float* __restrict__ b_hh1,
    const float* __restrict__ wf, const float* __restrict__ bf,
    const float* __restrict__ wn, const float* __restrict__ bn,
    float* __restrict__ out)
{
    const int tid = threadIdx.x;
    const int l   = tid & 63;
    const int w   = tid >> 6;            // wave id = gate type (0=i,1=f,2=g,3=o)
    const int wt  = __builtin_amdgcn_readfirstlane(w);
    const int col = l & 15;              // N-col (gate within tile) / A-row (batch)
    const int kg  = l >> 4;              // k-group
    const int ub  = tid >> 5;            // state-update: batch 0..7
    const int uu  = tid & 31;            // state-update: hidden unit 0..31

    // LDS: x fragments 64KB + h frags (80B rows: conflict-free b128) + gate exch
    __shared__ __align__(16) short xfrag[TT][BPB][8];   // [t][b][k0..7] bf16, k>=6 = 0
    __shared__ __align__(16) short h1f[16][40];         // rows 8..15 stay zero
    __shared__ __align__(16) short h2f[16][40];
    __shared__ __align__(16) float act1[BPB][4][32];    // [b][type][unit]
    __shared__ __align__(16) float act2[BPB][4][32];
    __shared__ __align__(16) float lasth[BPB][32];
    __shared__ __align__(16) short zbuf[8];

    // ---- init zero state
    {
        short* p1 = &h1f[0][0];
        short* p2 = &h2f[0][0];
        for (int i = tid; i < 16 * 40; i += 256) { p1[i] = 0; p2[i] = 0; }
        if (tid < 8) zbuf[tid] = 0;
    }

    // ---- stage x into bf16 A-fragment layout
    {
        const int bg0 = blockIdx.x * BPB;
        for (int p = tid; p < BPB * TT; p += 256) {
            const int b = p >> 9;            // 0..7
            const int t = p & (TT - 1);
            const float* src = imu + ((size_t)(bg0 + b) * TT + t) * 6;
            float2 a0 = *(const float2*)(src);
            float2 a1 = *(const float2*)(src + 2);
            float2 a2 = *(const float2*)(src + 4);
            unsigned* dst = (unsigned*)&xfrag[t][b][0];
            dst[0] = (unsigned short)f2bf(a0.x) | ((unsigned)(unsigned short)f2bf(a0.y) << 16);
            dst[1] = (unsigned short)f2bf(a1.x) | ((unsigned)(unsigned short)f2bf(a1.y) << 16);
            dst[2] = (unsigned short)f2bf(a2.x) | ((unsigned)(unsigned short)f2bf(a2.y) << 16);
            dst[3] = 0u;
        }
    }

    // ---- resident B-fragments (weights), biases
    const int G0 = 32 * w + col;         // first owned gate of this lane
    const int G1 = G0 + 16;              // second tile's gate
    short8 Bhh0_0 = load_bfrag(w_hh0, G0, kg), Bhh0_1 = load_bfrag(w_hh0, G1, kg);
    short8 Bih1_0 = load_bfrag(w_ih1, G0, kg), Bih1_1 = load_bfrag(w_ih1, G1, kg);
    short8 Bhh1_0 = load_bfrag(w_hh1, G0, kg), Bhh1_1 = load_bfrag(w_hh1, G1, kg);
    short8 Bx_0 = {0,0,0,0,0,0,0,0};
    short8 Bx_1 = {0,0,0,0,0,0,0,0};
    if (kg == 0) {
        #pragma unroll
        for (int j = 0; j < 6; ++j) {
            Bx_0[j] = f2bf(w_ih0[G0 * 6 + j]);
            Bx_1[j] = f2bf(w_ih0[G1 * 6 + j]);
        }
    }
    const float bias1_0 = b_ih0[G0] + b_hh0[G0];
    const float bias1_1 = b_ih0[G1] + b_hh0[G1];
    const float bias2_0 = b_ih1[G0] + b_hh1[G0];
    const float bias2_1 = b_ih1[G1] + b_hh1[G1];

    float c1 = 0.f, c2 = 0.f;
    const short8* hA1 = (const short8*)&h1f[col][kg * 8];
    const short8* hA2 = (const short8*)&h2f[col][kg * 8];
    __syncthreads();

    #pragma unroll 1
    for (int t = 0; t < TT; ++t) {
        // ======== P1: layer-1 gates (MFMA) + activation ========
        {
            short8 ah = *hA1;
            short8 ax = (l < 8) ? *(const short8*)&xfrag[t][l][0]
                                : *(const short8*)zbuf;
            f32x4 acc0 = {bias1_0, bias1_0, bias1_0, bias1_0};
            f32x4 acc1 = {bias1_1, bias1_1, bias1_1, bias1_1};
            acc0 = __builtin_amdgcn_mfma_f32_16x16x32_bf16(ax, Bx_0,   acc0, 0, 0, 0);
            acc1 = __builtin_amdgcn_mfma_f32_16x16x32_bf16(ax, Bx_1,   acc1, 0, 0, 0);
            acc0 = __builtin_amdgcn_mfma_f32_16x16x32_bf16(ah, Bhh0_0, acc0, 0, 0, 0);
            acc1 = __builtin_amdgcn_mfma_f32_16x16x32_bf16(ah, Bhh0_1, acc1, 0, 0, 0);
            if (l < 32) {   // valid batches: rows = kg*4+r in 0..7
                #pragma unroll
                for (int r = 0; r < 4; ++r) {
                    float v0 = acc0[r], v1 = acc1[r];
                    if (wt == 2) { v0 = tanh_fast(v0); v1 = tanh_fast(v1); }
                    else         { v0 = sigm(v0);      v1 = sigm(v1); }
                    const int b = kg * 4 + r;
                    act1[b][w][col]      = v0;
                    act1[b][w][col + 16] = v1;
                }
            }
        }
        __syncthreads();   // A: act1 ready

        // ======== P2: layer-1 state update ========
        {
            float gi = act1[ub][0][uu];
            float gf = act1[ub][1][uu];
            float gg = act1[ub][2][uu];
            float go = act1[ub][3][uu];
            c1 = gf * c1 + gi * gg;
            float h = go * tanh_fast(c1);
            h1f[ub][uu] = f2bf(h);
        }
        __syncthreads();   // B: h1 ready

        // ======== P3: layer-2 gates (MFMA) + activation ========
        {
            short8 a1 = *hA1;
            short8 a2 = *hA2;
            f32x4 d0 = {bias2_0, bias2_0, bias2_0, bias2_0};
            f32x4 d1 = {bias2_1, bias2_1, bias2_1, bias2_1};
            d0 = __builtin_amdgcn_mfma_f32_16x16x32_bf16(a1, Bih1_0, d0, 0, 0, 0);
            d1 = __builtin_amdgcn_mfma_f32_16x16x32_bf16(a1, Bih1_1, d1, 0, 0, 0);
            d0 = __builtin_amdgcn_mfma_f32_16x16x32_bf16(a2, Bhh1_0, d0, 0, 0, 0);
            d1 = __builtin_amdgcn_mfma_f32_16x16x32_bf16(a2, Bhh1_1, d1, 0, 0, 0);
            if (l < 32) {
                #pragma unroll
                for (int r = 0; r < 4; ++r) {
                    float v0 = d0[r], v1 = d1[r];
                    if (wt == 2) { v0 = tanh_fast(v0); v1 = tanh_fast(v1); }
                    else         { v0 = sigm(v0);      v1 = sigm(v1); }
                    const int b = kg * 4 + r;
                    act2[b][w][col]      = v0;
                    act2[b][w][col + 16] = v1;
                }
            }
        }
        __syncthreads();   // C: act2 ready

        // ======== P4: layer-2 state update (no barrier; next A covers it) ====
        {
            float gi = act2[ub][0][uu];
            float gf = act2[ub][1][uu];
            float gg = act2[ub][2][uu];
            float go = act2[ub][3][uu];
            c2 = gf * c2 + gi * gg;
            float h = go * tanh_fast(c2);
            h2f[ub][uu] = f2bf(h);
            if (t == TT - 1) lasth[ub][uu] = h;
        }
    }
    __syncthreads();

    // ======== heads: a = last@wf^T + bf ; R = exp(last@wn^T + bn) ========
    const int bg0 = blockIdx.x * BPB;
    #pragma unroll
    for (int rep = 0; rep < 2; ++rep) {
        const int idx = tid + rep * 256;   // 0..511
        const int b = idx >> 6;            // 0..7
        const int o = idx & 63;
        float accF = bf[o], accN = bn[o];
        const float4* wf4 = (const float4*)(wf + o * 32);
        const float4* wn4 = (const float4*)(wn + o * 32);
        const float4* hv4 = (const float4*)&lasth[b][0];
        #pragma unroll
        for (int k = 0; k < 8; ++k) {
            float4 h4 = hv4[k];
            float4 f4 = wf4[k];
            float4 n4 = wn4[k];
            accF += f4.x * h4.x + f4.y * h4.y + f4.z * h4.z + f4.w * h4.w;
            accN += n4.x * h4.x + n4.y * h4.y + n4.z * h4.z + n4.w * h4.w;
        }
        const size_t bg = bg0 + b;
        out[bg * OUTD + o] = accF;
        out[(size_t)2048 * OUTD + bg * OUTD + o] = __expf(accN);
    }
}

extern "C" void kernel_launch(void* const* d_in, const int* in_sizes, int n_in,
                              void* d_out, int out_size, void* d_ws, size_t ws_size,
                              hipStream_t stream) {
    const float* imu   = (const float*)d_in[0];
    const float* w_ih0 = (const float*)d_in[1];
    const float* w_hh0 = (const float*)d_in[2];
    const float* b_ih0 = (const float*)d_in[3];
    const float* b_hh0 = (const float*)d_in[4];
    const float* w_ih1 = (const float*)d_in[5];
    const float* w_hh1 = (const float*)d_in[6];
    const float* b_ih1 = (const float*)d_in[7];
    const float* b_hh1 = (const float*)d_in[8];
    const float* wf    = (const float*)d_in[9];
    const float* bf    = (const float*)d_in[10];
    const float* wn    = (const float*)d_in[11];
    const float* bn    = (const float*)d_in[12];
    float* out = (float*)d_out;

    lstm2_mfma_kernel<<<dim3(NBLK), dim3(256), 0, stream>>>(
        imu, w_ih0, w_hh0, b_ih0, b_hh0,
        w_ih1, w_hh1, b_ih1, b_hh1,
        wf, bf, wn, bn, out);
}

// Round 4
// 297.056 us; speedup vs baseline: 3.6068x; 1.6518x over previous
//
#include <hip/hip_runtime.h>

#define TT 512
#define BPB 8                 // batches per block
#define NBLK (2048 / BPB)     // 256 blocks = 1 per CU
#define OUTD 64

typedef __attribute__((ext_vector_type(8))) short short8;
typedef __attribute__((ext_vector_type(4))) float f32x4;

__device__ __forceinline__ short f2bf(float x) {  // RNE float->bf16
    union { float f; unsigned u; } v; v.f = x;
    unsigned r = (v.u + 0x7FFFu + ((v.u >> 16) & 1u)) >> 16;
    return (short)r;
}
__device__ __forceinline__ float sigm(float x) {
    return __builtin_amdgcn_rcpf(1.f + __expf(-x));
}
__device__ __forceinline__ float tanh_fast(float x) {
    return 2.f * sigm(2.f * x) - 1.f;
}

// B-fragment for 16x16x32 bf16: lane holds B[k][col], col=l&15, k=kg*8+j.
// W row-major [128][32]; B = W^T.
__device__ __forceinline__ short8 load_bfrag(const float* __restrict__ W, int G, int kg) {
    const float4 f0 = *(const float4*)(W + G * 32 + kg * 8);
    const float4 f1 = *(const float4*)(W + G * 32 + kg * 8 + 4);
    short8 r;
    r[0] = f2bf(f0.x); r[1] = f2bf(f0.y); r[2] = f2bf(f0.z); r[3] = f2bf(f0.w);
    r[4] = f2bf(f1.x); r[5] = f2bf(f1.y); r[6] = f2bf(f1.z); r[7] = f2bf(f1.w);
    return r;
}

__global__ __launch_bounds__(512, 1) void lstm2_pipe_kernel(
    const float* __restrict__ imu,
    const float* __restrict__ w_ih0, const float* __restrict__ w_hh0,
    const float* __restrict__ b_ih0, const float* __restrict__ b_hh0,
    const float* __restrict__ w_ih1, const float* __restrict__ w_hh1,
    const float* __restrict__ b_ih1, const float* __restrict__ b_hh1,
    const float* __restrict__ wf, const float* __restrict__ bf,
    const float* __restrict__ wn, const float* __restrict__ bn,
    float* __restrict__ out)
{
    const int tid   = threadIdx.x;
    const int l     = tid & 63;
    const int w     = tid >> 6;          // 8 waves
    const int layer = w >> 2;            // 0: LSTM layer 1, 1: LSTM layer 2
    const int gt    = w & 3;             // gate type 0=i,1=f,2=g,3=o
    const int col   = l & 15;
    const int kg    = l >> 4;

    __shared__ __align__(16) short xfrag[TT][BPB][8];   // bf16 A-frag layout, k>=6 zero
    __shared__ __align__(16) short h1f[16][40];         // rows 8..15 stay zero (80B row)
    __shared__ __align__(16) short h2f[16][40];
    __shared__ __align__(16) float act1[BPB][4][32];    // [b][type][unit]
    __shared__ __align__(16) float act2[BPB][4][32];
    __shared__ __align__(16) float lasth[BPB][32];

    // ---- init zero state
    {
        short* p1 = &h1f[0][0];
        short* p2 = &h2f[0][0];
        for (int i = tid; i < 16 * 40; i += 512) { p1[i] = 0; p2[i] = 0; }
    }

    // ---- stage x into bf16 A-fragment layout
    {
        const int bg0 = blockIdx.x * BPB;
        for (int p = tid; p < BPB * TT; p += 512) {
            const int b = p >> 9;            // 0..7
            const int t = p & (TT - 1);
            const float* src = imu + ((size_t)(bg0 + b) * TT + t) * 6;
            float2 a0 = *(const float2*)(src);
            float2 a1 = *(const float2*)(src + 2);
            float2 a2 = *(const float2*)(src + 4);
            unsigned* dst = (unsigned*)&xfrag[t][b][0];
            dst[0] = (unsigned short)f2bf(a0.x) | ((unsigned)(unsigned short)f2bf(a0.y) << 16);
            dst[1] = (unsigned short)f2bf(a1.x) | ((unsigned)(unsigned short)f2bf(a1.y) << 16);
            dst[2] = (unsigned short)f2bf(a2.x) | ((unsigned)(unsigned short)f2bf(a2.y) << 16);
            dst[3] = 0u;
        }
    }

    // ---- resident B-fragments: this wave owns gate-type gt of its layer,
    // two 16-col tiles: gates G0 = gt*32+col, G1 = G0+16.
    const int G0 = gt * 32 + col;
    const int G1 = G0 + 16;
    short8 Bf0, Bf1, Bs0, Bs1;   // first/second mfma B operands
    float bias0, bias1;
    if (layer == 0) {
        // acc = x@Wih0^T + bias;  acc += h1@Whh0^T
        Bf0 = (short8)0; Bf1 = (short8)0;
        if (kg == 0) {
            #pragma unroll
            for (int j = 0; j < 6; ++j) {
                Bf0[j] = f2bf(w_ih0[G0 * 6 + j]);
                Bf1[j] = f2bf(w_ih0[G1 * 6 + j]);
            }
        }
        Bs0 = load_bfrag(w_hh0, G0, kg);
        Bs1 = load_bfrag(w_hh0, G1, kg);
        bias0 = b_ih0[G0] + b_hh0[G0];
        bias1 = b_ih0[G1] + b_hh0[G1];
    } else {
        // acc = h1@Wih1^T + bias;  acc += h2@Whh1^T
        Bf0 = load_bfrag(w_ih1, G0, kg);
        Bf1 = load_bfrag(w_ih1, G1, kg);
        Bs0 = load_bfrag(w_hh1, G0, kg);
        Bs1 = load_bfrag(w_hh1, G1, kg);
        bias0 = b_ih1[G0] + b_hh1[G0];
        bias1 = b_ih1[G1] + b_hh1[G1];
    }
    const f32x4 binit0 = {bias0, bias0, bias0, bias0};
    const f32x4 binit1 = {bias1, bias1, bias1, bias1};

    const short8* hA1 = (const short8*)&h1f[col][kg * 8];
    const short8* hA2 = (const short8*)&h2f[col][kg * 8];
    float* actw = layer ? &act2[0][gt][0] : &act1[0][gt][0];  // + b*128 + unit

    // update-thread mapping: tid<256 -> layer-1 state, tid>=256 -> layer-2 state
    const int ub = (tid & 255) >> 5;     // batch 0..7
    const int uu = tid & 31;             // unit 0..31
    float cst = 0.f;                     // c1 (low waves) or c2 (high waves)

    __syncthreads();

    // ======== prologue: L1 gates for t=0 (h1=0) ========
    if (layer == 0) {
        short8 ax = (short8)0;
        if (l < 8) ax = *(const short8*)&xfrag[0][l][0];
        short8 ah = *hA1;  // zeros
        f32x4 a0 = binit0, a1 = binit1;
        a0 = __builtin_amdgcn_mfma_f32_16x16x32_bf16(ax, Bf0, a0, 0, 0, 0);
        a1 = __builtin_amdgcn_mfma_f32_16x16x32_bf16(ax, Bf1, a1, 0, 0, 0);
        a0 = __builtin_amdgcn_mfma_f32_16x16x32_bf16(ah, Bs0, a0, 0, 0, 0);
        a1 = __builtin_amdgcn_mfma_f32_16x16x32_bf16(ah, Bs1, a1, 0, 0, 0);
        if (l < 32) {
            #pragma unroll
            for (int r = 0; r < 4; ++r) {
                float v0 = a0[r], v1 = a1[r];
                if (gt == 2) { v0 = tanh_fast(v0); v1 = tanh_fast(v1); }
                else         { v0 = sigm(v0);      v1 = sigm(v1); }
                const int b = kg * 4 + r;
                actw[b * 128 + col]      = v0;
                actw[b * 128 + col + 16] = v1;
            }
        }
    }
    __syncthreads();
    if (tid < 256) {
        float gi = act1[ub][0][uu], gf = act1[ub][1][uu];
        float gg = act1[ub][2][uu], go = act1[ub][3][uu];
        cst = gf * cst + gi * gg;
        h1f[ub][uu] = f2bf(go * tanh_fast(cst));
    }
    __syncthreads();

    // ======== main loop: phase A = L1(t+1) || L2(t); phase B = both updates ====
    #pragma unroll 1
    for (int t = 0; t < TT - 1; ++t) {
        {
            short8 af, as;
            if (layer == 0) {
                af = (short8)0;
                if (l < 8) af = *(const short8*)&xfrag[t + 1][l][0];
                as = *hA1;
            } else {
                af = *hA1;
                as = *hA2;
            }
            f32x4 a0 = binit0, a1 = binit1;
            a0 = __builtin_amdgcn_mfma_f32_16x16x32_bf16(af, Bf0, a0, 0, 0, 0);
            a1 = __builtin_amdgcn_mfma_f32_16x16x32_bf16(af, Bf1, a1, 0, 0, 0);
            a0 = __builtin_amdgcn_mfma_f32_16x16x32_bf16(as, Bs0, a0, 0, 0, 0);
            a1 = __builtin_amdgcn_mfma_f32_16x16x32_bf16(as, Bs1, a1, 0, 0, 0);
            if (l < 32) {
                #pragma unroll
                for (int r = 0; r < 4; ++r) {
                    float v0 = a0[r], v1 = a1[r];
                    if (gt == 2) { v0 = tanh_fast(v0); v1 = tanh_fast(v1); }
                    else         { v0 = sigm(v0);      v1 = sigm(v1); }
                    const int b = kg * 4 + r;
                    actw[b * 128 + col]      = v0;
                    actw[b * 128 + col + 16] = v1;
                }
            }
        }
        __syncthreads();   // acts ready
        if (tid < 256) {   // layer-1 state -> h1(t+1)
            float gi = act1[ub][0][uu], gf = act1[ub][1][uu];
            float gg = act1[ub][2][uu], go = act1[ub][3][uu];
            cst = gf * cst + gi * gg;
            h1f[ub][uu] = f2bf(go * tanh_fast(cst));
        } else {           // layer-2 state -> h2(t)
            float gi = act2[ub][0][uu], gf = act2[ub][1][uu];
            float gg = act2[ub][2][uu], go = act2[ub][3][uu];
            cst = gf * cst + gi * gg;
            h2f[ub][uu] = f2bf(go * tanh_fast(cst));
        }
        __syncthreads();   // h ready
    }

    // ======== epilogue: L2(511) ========
    if (layer == 1) {
        short8 af = *hA1;
        short8 as = *hA2;
        f32x4 a0 = binit0, a1 = binit1;
        a0 = __builtin_amdgcn_mfma_f32_16x16x32_bf16(af, Bf0, a0, 0, 0, 0);
        a1 = __builtin_amdgcn_mfma_f32_16x16x32_bf16(af, Bf1, a1, 0, 0, 0);
        a0 = __builtin_amdgcn_mfma_f32_16x16x32_bf16(as, Bs0, a0, 0, 0, 0);
        a1 = __builtin_amdgcn_mfma_f32_16x16x32_bf16(as, Bs1, a1, 0, 0, 0);
        if (l < 32) {
            #pragma unroll
            for (int r = 0; r < 4; ++r) {
                float v0 = a0[r], v1 = a1[r];
                if (gt == 2) { v0 = tanh_fast(v0); v1 = tanh_fast(v1); }
                else         { v0 = sigm(v0);      v1 = sigm(v1); }
                const int b = kg * 4 + r;
                actw[b * 128 + col]      = v0;
                actw[b * 128 + col + 16] = v1;
            }
        }
    }
    __syncthreads();
    if (tid >= 256) {      // final layer-2 update -> lasth (keep fp32)
        float gi = act2[ub][0][uu], gf = act2[ub][1][uu];
        float gg = act2[ub][2][uu], go = act2[ub][3][uu];
        cst = gf * cst + gi * gg;
        lasth[ub][uu] = go * tanh_fast(cst);
    }
    __syncthreads();

    // ======== heads: 512 threads = 8 batches x 64 outputs ========
    {
        const int b = tid >> 6;            // 0..7 (wave-uniform)
        const int o = tid & 63;
        float accF = bf[o], accN = bn[o];
        const float4* wf4 = (const float4*)(wf + o * 32);
        const float4* wn4 = (const float4*)(wn + o * 32);
        const float4* hv4 = (const float4*)&lasth[b][0];
        #pragma unroll
        for (int k = 0; k < 8; ++k) {
            float4 h4 = hv4[k];
            float4 f4 = wf4[k];
            float4 n4 = wn4[k];
            accF += f4.x * h4.x + f4.y * h4.y + f4.z * h4.z + f4.w * h4.w;
            accN += n4.x * h4.x + n4.y * h4.y + n4.z * h4.z + n4.w * h4.w;
        }
        const size_t bg = (size_t)blockIdx.x * BPB + b;
        out[bg * OUTD + o] = accF;
        out[(size_t)2048 * OUTD + bg * OUTD + o] = __expf(accN);
    }
}

extern "C" void kernel_launch(void* const* d_in, const int* in_sizes, int n_in,
                              void* d_out, int out_size, void* d_ws, size_t ws_size,
                              hipStream_t stream) {
    const float* imu   = (const float*)d_in[0];
    const float* w_ih0 = (const float*)d_in[1];
    const float* w_hh0 = (const float*)d_in[2];
    const float* b_ih0 = (const float*)d_in[3];
    const float* b_hh0 = (const float*)d_in[4];
    const float* w_ih1 = (const float*)d_in[5];
    const float* w_hh1 = (const float*)d_in[6];
    const float* b_ih1 = (const float*)d_in[7];
    const float* b_hh1 = (const float*)d_in[8];
    const float* wf    = (const float*)d_in[9];
    const float* bf    = (const float*)d_in[10];
    const float* wn    = (const float*)d_in[11];
    const float* bn    = (const float*)d_in[12];
    float* out = (float*)d_out;

    lstm2_pipe_kernel<<<dim3(NBLK), dim3(512), 0, stream>>>(
        imu, w_ih0, w_hh0, b_ih0, b_hh0,
        w_ih1, w_hh1, b_ih1, b_hh1,
        wf, bf, wn, bn, out);
}

// Round 6
// 216.130 us; speedup vs baseline: 4.9573x; 1.3744x over previous
//
#include <hip/hip_runtime.h>

#define TT 512
#define BPB 8                 // batches per block
#define NBLK (2048 / BPB)     // 256 blocks = 1 per CU
#define OUTD 64

typedef __attribute__((ext_vector_type(8))) short short8;
typedef __attribute__((ext_vector_type(4))) float f32x4;

__device__ __forceinline__ short f2bf(float x) {  // RNE float->bf16
    union { float f; unsigned u; } v; v.f = x;
    unsigned r = (v.u + 0x7FFFu + ((v.u >> 16) & 1u)) >> 16;
    return (short)r;
}
__device__ __forceinline__ float sigm(float x) {
    return __builtin_amdgcn_rcpf(1.f + __expf(-x));
}
__device__ __forceinline__ float tanh_fast(float x) {
    return 2.f * sigm(2.f * x) - 1.f;
}

// In-lane LSTM cell update: acc regs = {i,f,g,o} for (unit,batch)
#define ACT_UPDATE(acc, c, hval)                                   \
    {                                                              \
        float gi = sigm((acc)[0]);                                 \
        float gf = sigm((acc)[1]);                                 \
        float gg = tanh_fast((acc)[2]);                            \
        float go = sigm((acc)[3]);                                 \
        (c) = gf * (c) + gi * gg;                                  \
        (hval) = go * tanh_fast((c));                              \
    }

__global__ __launch_bounds__(512, 1) void lstm2_inlane_kernel(
    const float* __restrict__ imu,
    const float* __restrict__ w_ih0, const float* __restrict__ w_hh0,
    const float* __restrict__ b_ih0, const float* __restrict__ b_hh0,
    const float* __restrict__ w_ih1, const float* __restrict__ w_hh1,
    const float* __restrict__ b_ih1, const float* __restrict__ b_hh1,
    const float* __restrict__ wf, const float* __restrict__ bf,
    const float* __restrict__ wn, const float* __restrict__ bn,
    float* __restrict__ out)
{
    const int tid   = threadIdx.x;
    const int l     = tid & 63;
    const int w     = tid >> 6;          // 8 waves
    const int layer = w >> 2;            // 0: LSTM1, 1: LSTM2
    const int pair  = w & 3;             // which pair of 16-gate tiles
    const int col   = l & 15;            // B col = batch; also A row index m
    const int kg    = l >> 4;            // k-group (and D row-quad q)

    __shared__ __align__(16) short xfrag[TT][8][8];    // [t][batch][k] bf16 (k>=6 zero)
    __shared__ __align__(16) short h1f[2][16][40];     // [parity][batch][unit] bf16
    __shared__ __align__(16) short h2f[2][16][40];
    __shared__ __align__(16) float lasth[16][36];      // [batch][unit] fp32

    // ---- zero h buffers
    {
        short* p1 = &h1f[0][0][0];
        short* p2 = &h2f[0][0][0];
        for (int i = tid; i < 2 * 16 * 40; i += 512) { p1[i] = 0; p2[i] = 0; }
    }

    // ---- stage x into [t][batch][k] bf16
    {
        const int bg0 = blockIdx.x * BPB;
        for (int p = tid; p < BPB * TT; p += 512) {
            const int b = p >> 9;            // 0..7
            const int t = p & (TT - 1);
            const float* src = imu + ((size_t)(bg0 + b) * TT + t) * 6;
            float2 a0 = *(const float2*)(src);
            float2 a1 = *(const float2*)(src + 2);
            float2 a2 = *(const float2*)(src + 4);
            unsigned* dst = (unsigned*)&xfrag[t][b][0];
            dst[0] = (unsigned short)f2bf(a0.x) | ((unsigned)(unsigned short)f2bf(a0.y) << 16);
            dst[1] = (unsigned short)f2bf(a1.x) | ((unsigned)(unsigned short)f2bf(a1.y) << 16);
            dst[2] = (unsigned short)f2bf(a2.x) | ((unsigned)(unsigned short)f2bf(a2.y) << 16);
            dst[3] = 0u;
        }
    }

    // ---- A-fragments: rows = weight rows, unit-major gate order.
    // tile tau covers units 4*tau..4*tau+3; frag row m -> gate G = (m&3)*32 + 4*tau + (m>>2)
    const int t0 = pair * 2, t1 = t0 + 1;
    const int m  = col;
    const int G0 = (m & 3) * 32 + t0 * 4 + (m >> 2);
    const int G1 = (m & 3) * 32 + t1 * 4 + (m >> 2);
    const int u0 = pair * 8 + kg;        // this lane's unit, tile0
    const int u1 = u0 + 4;               // tile1

    short8 A00, A01, A10, A11;           // [tile][first/second mfma]
    f32x4 bias0, bias1;
    if (layer == 0) {
        #pragma unroll
        for (int j = 0; j < 8; ++j) {
            A00[j] = (kg == 0 && j < 6) ? f2bf(w_ih0[G0 * 6 + j]) : (short)0;
            A10[j] = (kg == 0 && j < 6) ? f2bf(w_ih0[G1 * 6 + j]) : (short)0;
            A01[j] = f2bf(w_hh0[G0 * 32 + kg * 8 + j]);
            A11[j] = f2bf(w_hh0[G1 * 32 + kg * 8 + j]);
        }
        #pragma unroll
        for (int r = 0; r < 4; ++r) {
            bias0[r] = b_ih0[r * 32 + u0] + b_hh0[r * 32 + u0];
            bias1[r] = b_ih0[r * 32 + u1] + b_hh0[r * 32 + u1];
        }
    } else {
        #pragma unroll
        for (int j = 0; j < 8; ++j) {
            A00[j] = f2bf(w_ih1[G0 * 32 + kg * 8 + j]);
            A10[j] = f2bf(w_ih1[G1 * 32 + kg * 8 + j]);
            A01[j] = f2bf(w_hh1[G0 * 32 + kg * 8 + j]);
            A11[j] = f2bf(w_hh1[G1 * 32 + kg * 8 + j]);
        }
        #pragma unroll
        for (int r = 0; r < 4; ++r) {
            bias0[r] = b_ih1[r * 32 + u0] + b_hh1[r * 32 + u0];
            bias1[r] = b_ih1[r * 32 + u1] + b_hh1[r * 32 + u1];
        }
    }

    float c0 = 0.f, c1 = 0.f;            // per-lane cell states (2 units)

    const int xb = l & 7;                // batch whose x this lane feeds (cols 8-15 shadow 0-7)
    const short8* h1r0  = (const short8*)&h1f[0][col][kg * 8];
    const short8* h1r1  = (const short8*)&h1f[1][col][kg * 8];
    const short8* h2r0  = (const short8*)&h2f[0][col][kg * 8];
    const short8* h2r1  = (const short8*)&h2f[1][col][kg * 8];

    __syncthreads();

    // ======== prologue: L1 gates(0) with h1=0 ========
    if (layer == 0) {
        short8 xv = *(const short8*)&xfrag[0][xb][0];
        f32x4 a0 = bias0, a1 = bias1;
        a0 = __builtin_amdgcn_mfma_f32_16x16x32_bf16(A00, xv, a0, 0, 0, 0);
        a1 = __builtin_amdgcn_mfma_f32_16x16x32_bf16(A10, xv, a1, 0, 0, 0);
        float h0, h1v;
        ACT_UPDATE(a0, c0, h0);
        ACT_UPDATE(a1, c1, h1v);
        h1f[1][col][u0] = f2bf(h0);
        h1f[1][col][u1] = f2bf(h1v);
    }
    __syncthreads();

    // ======== main loop: iter t computes L1 gates(t+1) || L2 gates(t) ========
    // h1(T+1)/h2(T) written at parity T&1; h1(T)/h2(T-1) read at parity (T+1)&1.
#define STEP(T, H1R, H2R, WP)                                                   \
    {                                                                           \
        if (layer == 0) {                                                       \
            short8 xv = *(const short8*)&xfrag[(T) + 1][xb][0];                 \
            short8 hv = *(H1R);                                                 \
            f32x4 a0 = bias0, a1 = bias1;                                       \
            a0 = __builtin_amdgcn_mfma_f32_16x16x32_bf16(A00, xv, a0, 0, 0, 0); \
            a0 = __builtin_amdgcn_mfma_f32_16x16x32_bf16(A01, hv, a0, 0, 0, 0); \
            a1 = __builtin_amdgcn_mfma_f32_16x16x32_bf16(A10, xv, a1, 0, 0, 0); \
            a1 = __builtin_amdgcn_mfma_f32_16x16x32_bf16(A11, hv, a1, 0, 0, 0); \
            float h0, h1v;                                                      \
            ACT_UPDATE(a0, c0, h0);                                             \
            ACT_UPDATE(a1, c1, h1v);                                            \
            h1f[WP][col][u0] = f2bf(h0);                                        \
            h1f[WP][col][u1] = f2bf(h1v);                                       \
        } else {                                                                \
            short8 av = *(H1R);                                                 \
            short8 bv = *(H2R);                                                 \
            f32x4 a0 = bias0, a1 = bias1;                                       \
            a0 = __builtin_amdgcn_mfma_f32_16x16x32_bf16(A00, av, a0, 0, 0, 0); \
            a0 = __builtin_amdgcn_mfma_f32_16x16x32_bf16(A01, bv, a0, 0, 0, 0); \
            a1 = __builtin_amdgcn_mfma_f32_16x16x32_bf16(A10, av, a1, 0, 0, 0); \
            a1 = __builtin_amdgcn_mfma_f32_16x16x32_bf16(A11, bv, a1, 0, 0, 0); \
            float h0, h1v;                                                      \
            ACT_UPDATE(a0, c0, h0);                                             \
            ACT_UPDATE(a1, c1, h1v);                                            \
            h2f[WP][col][u0] = f2bf(h0);                                        \
            h2f[WP][col][u1] = f2bf(h1v);                                       \
        }                                                                       \
        __syncthreads();                                                        \
    }

    #pragma unroll 1
    for (int t = 0; t < TT - 2; t += 2) {
        STEP(t,     h1r1, h2r1, 0)   // even T: read parity 1, write parity 0
        STEP(t + 1, h1r0, h2r0, 1)   // odd  T: read parity 0, write parity 1
    }
    STEP(TT - 2, h1r1, h2r1, 0)      // T=510

    // ======== epilogue: L2 gates(511) -> lasth (fp32) ========
    if (layer == 1) {
        short8 av = *h1r0;           // h1(511) at parity 510&1 = 0
        short8 bv = *h2r0;           // h2(510) at parity 0
        f32x4 a0 = bias0, a1 = bias1;
        a0 = __builtin_amdgcn_mfma_f32_16x16x32_bf16(A00, av, a0, 0, 0, 0);
        a0 = __builtin_amdgcn_mfma_f32_16x16x32_bf16(A01, bv, a0, 0, 0, 0);
        a1 = __builtin_amdgcn_mfma_f32_16x16x32_bf16(A10, av, a1, 0, 0, 0);
        a1 = __builtin_amdgcn_mfma_f32_16x16x32_bf16(A11, bv, a1, 0, 0, 0);
        float h0, h1v;
        ACT_UPDATE(a0, c0, h0);
        ACT_UPDATE(a1, c1, h1v);
        lasth[col][u0] = h0;
        lasth[col][u1] = h1v;
    }
    __syncthreads();

    // ======== heads: 512 threads = 8 batches x 64 outputs ========
    {
        const int b = tid >> 6;            // 0..7 (wave-uniform)
        const int o = tid & 63;
        float accF = bf[o], accN = bn[o];
        const float4* wf4 = (const float4*)(wf + o * 32);
        const float4* wn4 = (const float4*)(wn + o * 32);
        const float4* hv4 = (const float4*)&lasth[b][0];
        #pragma unroll
        for (int k = 0; k < 8; ++k) {
            float4 h4 = hv4[k];
            float4 f4 = wf4[k];
            float4 n4 = wn4[k];
            accF += f4.x * h4.x + f4.y * h4.y + f4.z * h4.z + f4.w * h4.w;
            accN += n4.x * h4.x + n4.y * h4.y + n4.z * h4.z + n4.w * h4.w;
        }
        const size_t bg = (size_t)blockIdx.x * BPB + b;
        out[bg * OUTD + o] = accF;
        out[(size_t)2048 * OUTD + bg * OUTD + o] = __expf(accN);
    }
}

extern "C" void kernel_launch(void* const* d_in, const int* in_sizes, int n_in,
                              void* d_out, int out_size, void* d_ws, size_t ws_size,
                              hipStream_t stream) {
    const float* imu   = (const float*)d_in[0];
    const float* w_ih0 = (const float*)d_in[1];
    const float* w_hh0 = (const float*)d_in[2];
    const float* b_ih0 = (const float*)d_in[3];
    const float* b_hh0 = (const float*)d_in[4];
    const float* w_ih1 = (const float*)d_in[5];
    const float* w_hh1 = (const float*)d_in[6];
    const float* b_ih1 = (const float*)d_in[7];
    const float* b_hh1 = (const float*)d_in[8];
    const float* wf    = (const float*)d_in[9];
    const float* bf    = (const float*)d_in[10];
    const float* wn    = (const float*)d_in[11];
    const float* bn    = (const float*)d_in[12];
    float* out = (float*)d_out;

    lstm2_inlane_kernel<<<dim3(NBLK), dim3(512), 0, stream>>>(
        imu, w_ih0, w_hh0, b_ih0, b_hh0,
        w_ih1, w_hh1, b_ih1, b_hh1,
        wf, bf, wn, bn, out);
}

// Round 7
// 199.311 us; speedup vs baseline: 5.3756x; 1.0844x over previous
//
#include <hip/hip_runtime.h>
#include <hip/hip_bf16.h>

#define TT 512
#define BPB 8                 // batches per block
#define NBLK (2048 / BPB)     // 256 blocks = 1 per CU
#define OUTD 64

typedef __attribute__((ext_vector_type(8))) short short8;
typedef __attribute__((ext_vector_type(4))) float f32x4;

__device__ __forceinline__ short f2bf(float x) {  // RNE float->bf16
    union { float f; unsigned u; } v; v.f = x;
    unsigned r = (v.u + 0x7FFFu + ((v.u >> 16) & 1u)) >> 16;
    return (short)r;
}
__device__ __forceinline__ float sigm(float x) {
    return __builtin_amdgcn_rcpf(1.f + __expf(-x));
}
__device__ __forceinline__ float tanh_fast(float x) {
    return 2.f * sigm(2.f * x) - 1.f;
}

// In-lane LSTM cell update: acc regs = {i,f,g,o} for (unit,batch)
#define ACT_UPDATE(acc, c, hval)                                   \
    {                                                              \
        float gi = sigm((acc)[0]);                                 \
        float gf = sigm((acc)[1]);                                 \
        float gg = tanh_fast((acc)[2]);                            \
        float go = sigm((acc)[3]);                                 \
        (c) = gf * (c) + gi * gg;                                  \
        (hval) = go * tanh_fast((c));                              \
    }

// h K-slot permutation: unit u = p*8+r stored at slot p*8 + (r&3)*2 + (r>>2).
// => lane (pair,kg)'s two units (pair*8+kg, pair*8+kg+4) are ADJACENT slots
//    (pair*16+kg*4 bytes) -> single packed bf16x2 write, conflict-free.
// A-fragments must read W K-columns through the inverse: slot s holds unit
// perm(s) = (s&~7) + ((s&7)>>1) + (((s&7)&1)<<2).
__device__ __forceinline__ int kperm(int s) {
    int q = s & 7;
    return (s & ~7) + (q >> 1) + ((q & 1) << 2);
}

__global__ __launch_bounds__(512, 1) void lstm2_inlane_kernel(
    const float* __restrict__ imu,
    const float* __restrict__ w_ih0, const float* __restrict__ w_hh0,
    const float* __restrict__ b_ih0, const float* __restrict__ b_hh0,
    const float* __restrict__ w_ih1, const float* __restrict__ w_hh1,
    const float* __restrict__ b_ih1, const float* __restrict__ b_hh1,
    const float* __restrict__ wf, const float* __restrict__ bf,
    const float* __restrict__ wn, const float* __restrict__ bn,
    float* __restrict__ out)
{
    const int tid   = threadIdx.x;
    const int l     = tid & 63;
    const int w     = tid >> 6;          // 8 waves
    const int layer = w >> 2;            // 0: LSTM1, 1: LSTM2
    const int pair  = w & 3;             // which pair of 16-gate tiles
    const int col   = l & 15;            // B col = batch; also A row index m
    const int kg    = l >> 4;            // k-group (and D row-quad q)

    __shared__ __align__(16) short xfrag[TT + 2][8][8];  // [t][batch][k] bf16 (k>=6 zero); +2 pad rows for prefetch
    __shared__ __align__(16) short h1f[2][16][40];       // [parity][batch][slot] bf16
    __shared__ __align__(16) short h2f[2][16][40];
    __shared__ __align__(16) float lasth[16][36];        // [batch][unit] fp32

    // ---- zero h buffers
    {
        short* p1 = &h1f[0][0][0];
        short* p2 = &h2f[0][0][0];
        for (int i = tid; i < 2 * 16 * 40; i += 512) { p1[i] = 0; p2[i] = 0; }
    }

    // ---- stage x into [t][batch][k] bf16
    {
        const int bg0 = blockIdx.x * BPB;
        for (int p = tid; p < BPB * TT; p += 512) {
            const int b = p >> 9;            // 0..7
            const int t = p & (TT - 1);
            const float* src = imu + ((size_t)(bg0 + b) * TT + t) * 6;
            float2 a0 = *(const float2*)(src);
            float2 a1 = *(const float2*)(src + 2);
            float2 a2 = *(const float2*)(src + 4);
            unsigned* dst = (unsigned*)&xfrag[t][b][0];
            dst[0] = (unsigned short)f2bf(a0.x) | ((unsigned)(unsigned short)f2bf(a0.y) << 16);
            dst[1] = (unsigned short)f2bf(a1.x) | ((unsigned)(unsigned short)f2bf(a1.y) << 16);
            dst[2] = (unsigned short)f2bf(a2.x) | ((unsigned)(unsigned short)f2bf(a2.y) << 16);
            dst[3] = 0u;
        }
    }

    // ---- A-fragments: rows = weight rows, unit-major gate order.
    // tile tau covers units 4*tau..4*tau+3; frag row m -> gate G = (m&3)*32 + 4*tau + (m>>2)
    const int t0 = pair * 2, t1 = t0 + 1;
    const int m  = col;
    const int G0 = (m & 3) * 32 + t0 * 4 + (m >> 2);
    const int G1 = (m & 3) * 32 + t1 * 4 + (m >> 2);
    const int u0 = pair * 8 + kg;        // this lane's unit, tile0
    const int u1 = u0 + 4;               // tile1
    const int hslot = pair * 8 + kg * 2; // packed write slot (short index)

    short8 A00, A01, A10, A11;           // [tile][first/second mfma]
    f32x4 bias0, bias1;
    if (layer == 0) {
        #pragma unroll
        for (int j = 0; j < 8; ++j) {
            const int up = kg * 8 + (j >> 1) + ((j & 1) << 2);  // kperm(kg*8+j)
            A00[j] = (kg == 0 && j < 6) ? f2bf(w_ih0[G0 * 6 + j]) : (short)0;
            A10[j] = (kg == 0 && j < 6) ? f2bf(w_ih0[G1 * 6 + j]) : (short)0;
            A01[j] = f2bf(w_hh0[G0 * 32 + up]);
            A11[j] = f2bf(w_hh0[G1 * 32 + up]);
        }
        #pragma unroll
        for (int r = 0; r < 4; ++r) {
            bias0[r] = b_ih0[r * 32 + u0] + b_hh0[r * 32 + u0];
            bias1[r] = b_ih0[r * 32 + u1] + b_hh0[r * 32 + u1];
        }
    } else {
        #pragma unroll
        for (int j = 0; j < 8; ++j) {
            const int up = kg * 8 + (j >> 1) + ((j & 1) << 2);  // kperm(kg*8+j)
            A00[j] = f2bf(w_ih1[G0 * 32 + up]);
            A10[j] = f2bf(w_ih1[G1 * 32 + up]);
            A01[j] = f2bf(w_hh1[G0 * 32 + up]);
            A11[j] = f2bf(w_hh1[G1 * 32 + up]);
        }
        #pragma unroll
        for (int r = 0; r < 4; ++r) {
            bias0[r] = b_ih1[r * 32 + u0] + b_hh1[r * 32 + u0];
            bias1[r] = b_ih1[r * 32 + u1] + b_hh1[r * 32 + u1];
        }
    }

    float c0 = 0.f, c1 = 0.f;            // per-lane cell states (2 units)

    const int xb = l & 7;                // batch whose x this lane feeds (cols 8-15 shadow 0-7)
    const short8* h1r0  = (const short8*)&h1f[0][col][kg * 8];
    const short8* h1r1  = (const short8*)&h1f[1][col][kg * 8];
    const short8* h2r0  = (const short8*)&h2f[0][col][kg * 8];
    const short8* h2r1  = (const short8*)&h2f[1][col][kg * 8];

    __syncthreads();

    // ======== prologue: L1 gates(0) with h1=0 ========
    short8 xv_cur;                       // holds x(T+1) at STEP(T) entry
    if (layer == 0) {
        short8 xv = *(const short8*)&xfrag[0][xb][0];
        f32x4 a0 = bias0, a1 = bias1;
        a0 = __builtin_amdgcn_mfma_f32_16x16x32_bf16(A00, xv, a0, 0, 0, 0);
        a1 = __builtin_amdgcn_mfma_f32_16x16x32_bf16(A10, xv, a1, 0, 0, 0);
        float h0, h1v;
        ACT_UPDATE(a0, c0, h0);
        ACT_UPDATE(a1, c1, h1v);
        *reinterpret_cast<__hip_bfloat162*>(&h1f[1][col][hslot]) =
            __float22bfloat162_rn(make_float2(h0, h1v));
        xv_cur = *(const short8*)&xfrag[1][xb][0];
    }
    __syncthreads();

    // ======== main loop: iter T computes L1 gates(T+1) || L2 gates(T) ========
    // h1(T+1)/h2(T) written at parity T&1; read at parity (T+1)&1.
    // x(T+2) prefetched BEFORE the barrier (latency drains in barrier wait).
#define STEP(T, H1R, H2R, WP)                                                   \
    {                                                                           \
        if (layer == 0) {                                                       \
            short8 hv = *(H1R);                                                 \
            f32x4 a0 = bias0, a1 = bias1;                                       \
            a0 = __builtin_amdgcn_mfma_f32_16x16x32_bf16(A00, xv_cur, a0, 0, 0, 0); \
            a1 = __builtin_amdgcn_mfma_f32_16x16x32_bf16(A10, xv_cur, a1, 0, 0, 0); \
            a0 = __builtin_amdgcn_mfma_f32_16x16x32_bf16(A01, hv, a0, 0, 0, 0); \
            a1 = __builtin_amdgcn_mfma_f32_16x16x32_bf16(A11, hv, a1, 0, 0, 0); \
            float h0, h1v;                                                      \
            ACT_UPDATE(a0, c0, h0);                                             \
            ACT_UPDATE(a1, c1, h1v);                                            \
            *reinterpret_cast<__hip_bfloat162*>(&h1f[WP][col][hslot]) =         \
                __float22bfloat162_rn(make_float2(h0, h1v));                    \
            xv_cur = *(const short8*)&xfrag[(T) + 2][xb][0];                    \
        } else {                                                                \
            short8 av = *(H1R);                                                 \
            short8 bv = *(H2R);                                                 \
            f32x4 a0 = bias0, a1 = bias1;                                       \
            a0 = __builtin_amdgcn_mfma_f32_16x16x32_bf16(A00, av, a0, 0, 0, 0); \
            a0 = __builtin_amdgcn_mfma_f32_16x16x32_bf16(A01, bv, a0, 0, 0, 0); \
            a1 = __builtin_amdgcn_mfma_f32_16x16x32_bf16(A10, av, a1, 0, 0, 0); \
            a1 = __builtin_amdgcn_mfma_f32_16x16x32_bf16(A11, bv, a1, 0, 0, 0); \
            float h0, h1v;                                                      \
            ACT_UPDATE(a0, c0, h0);                                             \
            ACT_UPDATE(a1, c1, h1v);                                            \
            *reinterpret_cast<__hip_bfloat162*>(&h2f[WP][col][hslot]) =         \
                __float22bfloat162_rn(make_float2(h0, h1v));                    \
        }                                                                       \
        __syncthreads();                                                        \
    }

    #pragma unroll 1
    for (int t = 0; t < TT - 2; t += 2) {
        STEP(t,     h1r1, h2r1, 0)   // even T: read parity 1, write parity 0
        STEP(t + 1, h1r0, h2r0, 1)   // odd  T: read parity 0, write parity 1
    }
    STEP(TT - 2, h1r1, h2r1, 0)      // T=510 (prefetches pad row TT; unused)

    // ======== epilogue: L2 gates(511) -> lasth (fp32, natural unit idx) ========
    if (layer == 1) {
        short8 av = *h1r0;           // h1(511) at parity 510&1 = 0
        short8 bv = *h2r0;           // h2(510) at parity 0
        f32x4 a0 = bias0, a1 = bias1;
        a0 = __builtin_amdgcn_mfma_f32_16x16x32_bf16(A00, av, a0, 0, 0, 0);
        a0 = __builtin_amdgcn_mfma_f32_16x16x32_bf16(A01, bv, a0, 0, 0, 0);
        a1 = __builtin_amdgcn_mfma_f32_16x16x32_bf16(A10, av, a1, 0, 0, 0);
        a1 = __builtin_amdgcn_mfma_f32_16x16x32_bf16(A11, bv, a1, 0, 0, 0);
        float h0, h1v;
        ACT_UPDATE(a0, c0, h0);
        ACT_UPDATE(a1, c1, h1v);
        lasth[col][u0] = h0;
        lasth[col][u1] = h1v;
    }
    __syncthreads();

    // ======== heads: 512 threads = 8 batches x 64 outputs ========
    {
        const int b = tid >> 6;            // 0..7 (wave-uniform)
        const int o = tid & 63;
        float accF = bf[o], accN = bn[o];
        const float4* wf4 = (const float4*)(wf + o * 32);
        const float4* wn4 = (const float4*)(wn + o * 32);
        const float4* hv4 = (const float4*)&lasth[b][0];
        #pragma unroll
        for (int k = 0; k < 8; ++k) {
            float4 h4 = hv4[k];
            float4 f4 = wf4[k];
            float4 n4 = wn4[k];
            accF += f4.x * h4.x + f4.y * h4.y + f4.z * h4.z + f4.w * h4.w;
            accN += n4.x * h4.x + n4.y * h4.y + n4.z * h4.z + n4.w * h4.w;
        }
        const size_t bg = (size_t)blockIdx.x * BPB + b;
        out[bg * OUTD + o] = accF;
        out[(size_t)2048 * OUTD + bg * OUTD + o] = __expf(accN);
    }
}

extern "C" void kernel_launch(void* const* d_in, const int* in_sizes, int n_in,
                              void* d_out, int out_size, void* d_ws, size_t ws_size,
                              hipStream_t stream) {
    const float* imu   = (const float*)d_in[0];
    const float* w_ih0 = (const float*)d_in[1];
    const float* w_hh0 = (const float*)d_in[2];
    const float* b_ih0 = (const float*)d_in[3];
    const float* b_hh0 = (const float*)d_in[4];
    const float* w_ih1 = (const float*)d_in[5];
    const float* w_hh1 = (const float*)d_in[6];
    const float* b_ih1 = (const float*)d_in[7];
    const float* b_hh1 = (const float*)d_in[8];
    const float* wf    = (const float*)d_in[9];
    const float* bf    = (const float*)d_in[10];
    const float* wn    = (const float*)d_in[11];
    const float* bn    = (const float*)d_in[12];
    float* out = (float*)d_out;

    lstm2_inlane_kernel<<<dim3(NBLK), dim3(512), 0, stream>>>(
        imu, w_ih0, w_hh0, b_ih0, b_hh0,
        w_ih1, w_hh1, b_ih1, b_hh1,
        wf, bf, wn, bn, out);
}

// Round 8
// 174.224 us; speedup vs baseline: 6.1497x; 1.1440x over previous
//
#include <hip/hip_runtime.h>
#include <hip/hip_bf16.h>

#define TT 512
#define BPB 8                 // batches per block
#define NBLK (2048 / BPB)     // 256 blocks = 1 per CU
#define OUTD 64

typedef __attribute__((ext_vector_type(8))) short short8;
typedef __attribute__((ext_vector_type(4))) float f32x4;

__device__ __forceinline__ short f2bf(float x) {  // RNE float->bf16
    union { float f; unsigned u; } v; v.f = x;
    unsigned r = (v.u + 0x7FFFu + ((v.u >> 16) & 1u)) >> 16;
    return (short)r;
}
__device__ __forceinline__ float sigm(float x) {
    return __builtin_amdgcn_rcpf(1.f + __expf(-x));
}
__device__ __forceinline__ float tanh_fast(float x) {
    return 2.f * sigm(2.f * x) - 1.f;
}

// In-lane LSTM cell update: acc regs = {i,f,g,o} for this lane's (unit,batch)
#define ACT_UPDATE(acc, c, hval)                                   \
    {                                                              \
        float gi = sigm((acc)[0]);                                 \
        float gf = sigm((acc)[1]);                                 \
        float gg = tanh_fast((acc)[2]);                            \
        float go = sigm((acc)[3]);                                 \
        (c) = gf * (c) + gi * gg;                                  \
        (hval) = go * tanh_fast((c));                              \
    }

// Fold tile1's valid batch-columns (col<8) into tile0's junk columns (col>=8):
// lane (kg,col>=8) takes a1 from lane col-8 (same kg). After MERGE every lane
// holds {i,f,g,o} of ONE valid (unit,batch): unit = pair*8+kg+(col>=8?4:0),
// batch = col&7. Halves the transcendental count per wave.
#define MERGE(mg, a0, a1, colhi)                                   \
    {                                                              \
        _Pragma("unroll")                                          \
        for (int r = 0; r < 4; ++r) {                              \
            float s = __shfl_xor((a1)[r], 8);                      \
            (mg)[r] = (colhi) ? s : (a0)[r];                       \
        }                                                          \
    }

__global__ __launch_bounds__(512, 1) void lstm2_inlane_kernel(
    const float* __restrict__ imu,
    const float* __restrict__ w_ih0, const float* __restrict__ w_hh0,
    const float* __restrict__ b_ih0, const float* __restrict__ b_hh0,
    const float* __restrict__ w_ih1, const float* __restrict__ w_hh1,
    const float* __restrict__ b_ih1, const float* __restrict__ b_hh1,
    const float* __restrict__ wf, const float* __restrict__ bf,
    const float* __restrict__ wn, const float* __restrict__ bn,
    float* __restrict__ out)
{
    const int tid   = threadIdx.x;
    const int l     = tid & 63;
    const int w     = tid >> 6;          // 8 waves
    const int layer = w >> 2;            // 0: LSTM1, 1: LSTM2
    const int pair  = w & 3;             // which pair of 16-gate tiles
    const int col   = l & 15;            // B col = batch (0-7 valid); A row m
    const int kg    = l >> 4;            // k-group (and D row-quad)
    const bool colhi = (col >= 8);
    const int batch  = col & 7;

    __shared__ __align__(16) short xfrag[TT + 2][8][8];  // [t][batch][k] bf16 (k>=6 zero); +2 pad for prefetch
    __shared__ __align__(16) short h1f[2][16][40];       // [parity][batch][unit] bf16; rows 8-15 stay 0
    __shared__ __align__(16) short h2f[2][16][40];
    __shared__ __align__(16) float lasth[16][36];        // [batch][unit] fp32

    // ---- zero h buffers
    {
        short* p1 = &h1f[0][0][0];
        short* p2 = &h2f[0][0][0];
        for (int i = tid; i < 2 * 16 * 40; i += 512) { p1[i] = 0; p2[i] = 0; }
    }

    // ---- stage x into [t][batch][k] bf16
    {
        const int bg0 = blockIdx.x * BPB;
        for (int p = tid; p < BPB * TT; p += 512) {
            const int b = p >> 9;            // 0..7
            const int t = p & (TT - 1);
            const float* src = imu + ((size_t)(bg0 + b) * TT + t) * 6;
            float2 a0 = *(const float2*)(src);
            float2 a1 = *(const float2*)(src + 2);
            float2 a2 = *(const float2*)(src + 4);
            unsigned* dst = (unsigned*)&xfrag[t][b][0];
            dst[0] = (unsigned short)f2bf(a0.x) | ((unsigned)(unsigned short)f2bf(a0.y) << 16);
            dst[1] = (unsigned short)f2bf(a1.x) | ((unsigned)(unsigned short)f2bf(a1.y) << 16);
            dst[2] = (unsigned short)f2bf(a2.x) | ((unsigned)(unsigned short)f2bf(a2.y) << 16);
            dst[3] = 0u;
        }
    }

    // ---- A-fragments: rows = weight rows, unit-major gate order (natural K).
    // frag row m -> gate G = (m&3)*32 + tau*4 + (m>>2); acc reg r = gate type r.
    const int t0 = pair * 2, t1 = t0 + 1;
    const int m  = col;
    const int G0 = (m & 3) * 32 + t0 * 4 + (m >> 2);
    const int G1 = (m & 3) * 32 + t1 * 4 + (m >> 2);
    const int u0 = pair * 8 + kg;        // tile0 unit of this lane
    const int u1 = u0 + 4;               // tile1 unit
    const int myunit = u0 + (colhi ? 4 : 0);   // owned (unit) after MERGE

    short8 A00, A01, A10, A11;           // [tile][first/second mfma]
    f32x4 bias0, bias1;
    if (layer == 0) {
        #pragma unroll
        for (int j = 0; j < 8; ++j) {
            A00[j] = (kg == 0 && j < 6) ? f2bf(w_ih0[G0 * 6 + j]) : (short)0;
            A10[j] = (kg == 0 && j < 6) ? f2bf(w_ih0[G1 * 6 + j]) : (short)0;
            A01[j] = f2bf(w_hh0[G0 * 32 + kg * 8 + j]);
            A11[j] = f2bf(w_hh0[G1 * 32 + kg * 8 + j]);
        }
        #pragma unroll
        for (int r = 0; r < 4; ++r) {
            bias0[r] = b_ih0[r * 32 + u0] + b_hh0[r * 32 + u0];
            bias1[r] = b_ih0[r * 32 + u1] + b_hh0[r * 32 + u1];
        }
    } else {
        #pragma unroll
        for (int j = 0; j < 8; ++j) {
            A00[j] = f2bf(w_ih1[G0 * 32 + kg * 8 + j]);
            A10[j] = f2bf(w_ih1[G1 * 32 + kg * 8 + j]);
            A01[j] = f2bf(w_hh1[G0 * 32 + kg * 8 + j]);
            A11[j] = f2bf(w_hh1[G1 * 32 + kg * 8 + j]);
        }
        #pragma unroll
        for (int r = 0; r < 4; ++r) {
            bias0[r] = b_ih1[r * 32 + u0] + b_hh1[r * 32 + u0];
            bias1[r] = b_ih1[r * 32 + u1] + b_hh1[r * 32 + u1];
        }
    }

    float c = 0.f;                       // this lane's single cell state

    const int xb = l & 7;                // batch whose x this lane feeds
    const short8* h1r0  = (const short8*)&h1f[0][col][kg * 8];
    const short8* h1r1  = (const short8*)&h1f[1][col][kg * 8];
    const short8* h2r0  = (const short8*)&h2f[0][col][kg * 8];
    const short8* h2r1  = (const short8*)&h2f[1][col][kg * 8];

    __syncthreads();

    // ======== prologue: L1 gates(0) with h1=0 ========
    short8 xv_cur;                       // holds x(T+1) at STEP(T) entry
    if (layer == 0) {
        short8 xv = *(const short8*)&xfrag[0][xb][0];
        f32x4 a0 = bias0, a1 = bias1;
        a0 = __builtin_amdgcn_mfma_f32_16x16x32_bf16(A00, xv, a0, 0, 0, 0);
        a1 = __builtin_amdgcn_mfma_f32_16x16x32_bf16(A10, xv, a1, 0, 0, 0);
        f32x4 mg;
        MERGE(mg, a0, a1, colhi);
        float h;
        ACT_UPDATE(mg, c, h);
        h1f[1][batch][myunit] = f2bf(h);
        xv_cur = *(const short8*)&xfrag[1][xb][0];
    }
    __syncthreads();

    // ======== main loop: iter T computes L1 gates(T+1) || L2 gates(T) ========
    // h1(T+1)/h2(T) written at parity T&1; read at parity (T+1)&1.
    // x(T+2) prefetched BEFORE the barrier (latency drains in barrier wait).
#define STEP(T, H1R, H2R, WP)                                                   \
    {                                                                           \
        if (layer == 0) {                                                       \
            short8 hv = *(H1R);                                                 \
            f32x4 a0 = bias0, a1 = bias1;                                       \
            a0 = __builtin_amdgcn_mfma_f32_16x16x32_bf16(A00, xv_cur, a0, 0, 0, 0); \
            a1 = __builtin_amdgcn_mfma_f32_16x16x32_bf16(A10, xv_cur, a1, 0, 0, 0); \
            a0 = __builtin_amdgcn_mfma_f32_16x16x32_bf16(A01, hv, a0, 0, 0, 0); \
            a1 = __builtin_amdgcn_mfma_f32_16x16x32_bf16(A11, hv, a1, 0, 0, 0); \
            f32x4 mg;                                                           \
            MERGE(mg, a0, a1, colhi);                                           \
            float h;                                                            \
            ACT_UPDATE(mg, c, h);                                               \
            h1f[WP][batch][myunit] = f2bf(h);                                   \
            xv_cur = *(const short8*)&xfrag[(T) + 2][xb][0];                    \
        } else {                                                                \
            short8 av = *(H1R);                                                 \
            short8 bv = *(H2R);                                                 \
            f32x4 a0 = bias0, a1 = bias1;                                       \
            a0 = __builtin_amdgcn_mfma_f32_16x16x32_bf16(A00, av, a0, 0, 0, 0); \
            a0 = __builtin_amdgcn_mfma_f32_16x16x32_bf16(A01, bv, a0, 0, 0, 0); \
            a1 = __builtin_amdgcn_mfma_f32_16x16x32_bf16(A10, av, a1, 0, 0, 0); \
            a1 = __builtin_amdgcn_mfma_f32_16x16x32_bf16(A11, bv, a1, 0, 0, 0); \
            f32x4 mg;                                                           \
            MERGE(mg, a0, a1, colhi);                                           \
            float h;                                                            \
            ACT_UPDATE(mg, c, h);                                               \
            h2f[WP][batch][myunit] = f2bf(h);                                   \
        }                                                                       \
        __syncthreads();                                                        \
    }

    #pragma unroll 1
    for (int t = 0; t < TT - 2; t += 2) {
        STEP(t,     h1r1, h2r1, 0)   // even T: read parity 1, write parity 0
        STEP(t + 1, h1r0, h2r0, 1)   // odd  T: read parity 0, write parity 1
    }
    STEP(TT - 2, h1r1, h2r1, 0)      // T=510 (prefetches pad row; unused)

    // ======== epilogue: L2 gates(511) -> lasth (fp32) ========
    if (layer == 1) {
        short8 av = *h1r0;           // h1(511) at parity 510&1 = 0
        short8 bv = *h2r0;           // h2(510) at parity 0
        f32x4 a0 = bias0, a1 = bias1;
        a0 = __builtin_amdgcn_mfma_f32_16x16x32_bf16(A00, av, a0, 0, 0, 0);
        a0 = __builtin_amdgcn_mfma_f32_16x16x32_bf16(A01, bv, a0, 0, 0, 0);
        a1 = __builtin_amdgcn_mfma_f32_16x16x32_bf16(A10, av, a1, 0, 0, 0);
        a1 = __builtin_amdgcn_mfma_f32_16x16x32_bf16(A11, bv, a1, 0, 0, 0);
        f32x4 mg;
        MERGE(mg, a0, a1, colhi);
        float h;
        ACT_UPDATE(mg, c, h);
        lasth[batch][myunit] = h;
    }
    __syncthreads();

    // ======== heads: 512 threads = 8 batches x 64 outputs ========
    {
        const int b = tid >> 6;            // 0..7 (wave-uniform)
        const int o = tid & 63;
        float accF = bf[o], accN = bn[o];
        const float4* wf4 = (const float4*)(wf + o * 32);
        const float4* wn4 = (const float4*)(wn + o * 32);
        const float4* hv4 = (const float4*)&lasth[b][0];
        #pragma unroll
        for (int k = 0; k < 8; ++k) {
            float4 h4 = hv4[k];
            float4 f4 = wf4[k];
            float4 n4 = wn4[k];
            accF += f4.x * h4.x + f4.y * h4.y + f4.z * h4.z + f4.w * h4.w;
            accN += n4.x * h4.x + n4.y * h4.y + n4.z * h4.z + n4.w * h4.w;
        }
        const size_t bg = (size_t)blockIdx.x * BPB + b;
        out[bg * OUTD + o] = accF;
        out[(size_t)2048 * OUTD + bg * OUTD + o] = __expf(accN);
    }
}

extern "C" void kernel_launch(void* const* d_in, const int* in_sizes, int n_in,
                              void* d_out, int out_size, void* d_ws, size_t ws_size,
                              hipStream_t stream) {
    const float* imu   = (const float*)d_in[0];
    const float* w_ih0 = (const float*)d_in[1];
    const float* w_hh0 = (const float*)d_in[2];
    const float* b_ih0 = (const float*)d_in[3];
    const float* b_hh0 = (const float*)d_in[4];
    const float* w_ih1 = (const float*)d_in[5];
    const float* w_hh1 = (const float*)d_in[6];
    const float* b_ih1 = (const float*)d_in[7];
    const float* b_hh1 = (const float*)d_in[8];
    const float* wf    = (const float*)d_in[9];
    const float* bf    = (const float*)d_in[10];
    const float* wn    = (const float*)d_in[11];
    const float* bn    = (const float*)d_in[12];
    float* out = (float*)d_out;

    lstm2_inlane_kernel<<<dim3(NBLK), dim3(512), 0, stream>>>(
        imu, w_ih0, w_hh0, b_ih0, b_hh0,
        w_ih1, w_hh1, b_ih1, b_hh1,
        wf, bf, wn, bn, out);
}

// Round 9
// 173.888 us; speedup vs baseline: 6.1616x; 1.0019x over previous
//
#include <hip/hip_runtime.h>
#include <hip/hip_bf16.h>

#define TT 512
#define BPB 8                 // batches per block
#define NBLK (2048 / BPB)     // 256 blocks = 1 per CU
#define OUTD 64

typedef __attribute__((ext_vector_type(8))) short short8;
typedef __attribute__((ext_vector_type(4))) float f32x4;

__device__ __forceinline__ short f2bf(float x) {  // RNE float->bf16 (staging only)
    union { float f; unsigned u; } v; v.f = x;
    unsigned r = (v.u + 0x7FFFu + ((v.u >> 16) & 1u)) >> 16;
    return (short)r;
}
__device__ __forceinline__ short cvt_bf16(float x) {  // 1-instr RNE cvt
    unsigned r;
    asm("v_cvt_pk_bf16_f32 %0, %1, %1" : "=v"(r) : "v"(x));
    return (short)r;
}
__device__ __forceinline__ float sigm(float x) {
    return __builtin_amdgcn_rcpf(1.f + __expf(-x));
}
__device__ __forceinline__ float tanh_fast(float x) {
    return 2.f * sigm(2.f * x) - 1.f;
}

// In-lane LSTM cell update: acc regs = {i,f,g,o} for this lane's (unit,batch)
#define ACT_UPDATE(acc, c, hval)                                   \
    {                                                              \
        float gi = sigm((acc)[0]);                                 \
        float gf = sigm((acc)[1]);                                 \
        float gg = tanh_fast((acc)[2]);                            \
        float go = sigm((acc)[3]);                                 \
        (c) = gf * (c) + gi * gg;                                  \
        (hval) = go * tanh_fast((c));                              \
    }

// Fold tile1's valid batch-columns (col<8) into tile0's junk columns (col>=8).
#define MERGE(mg, a0, a1, colhi)                                   \
    {                                                              \
        _Pragma("unroll")                                          \
        for (int r = 0; r < 4; ++r) {                              \
            float s = __shfl_xor((a1)[r], 8);                      \
            (mg)[r] = (colhi) ? s : (a0)[r];                       \
        }                                                          \
    }

__global__ __launch_bounds__(512, 1) void lstm2_inlane_kernel(
    const float* __restrict__ imu,
    const float* __restrict__ w_ih0, const float* __restrict__ w_hh0,
    const float* __restrict__ b_ih0, const float* __restrict__ b_hh0,
    const float* __restrict__ w_ih1, const float* __restrict__ w_hh1,
    const float* __restrict__ b_ih1, const float* __restrict__ b_hh1,
    const float* __restrict__ wf, const float* __restrict__ bf,
    const float* __restrict__ wn, const float* __restrict__ bn,
    float* __restrict__ out)
{
    const int tid   = threadIdx.x;
    const int l     = tid & 63;
    const int w     = tid >> 6;          // 8 waves
    const int layer = w >> 2;            // 0: LSTM1, 1: LSTM2
    const int pair  = w & 3;             // which pair of 16-gate tiles
    const int col   = l & 15;            // B col = batch (0-7 valid); A row m
    const int kg    = l >> 4;            // k-group (and D row-quad)
    const bool colhi = (col >= 8);
    const int batch  = col & 7;

    __shared__ __align__(16) short xfrag[TT + 4][8][8];  // [t][batch][k] bf16 (k>=6 zero); +4 pad for 3-deep prefetch
    __shared__ __align__(16) short h1f[2][16][40];       // [parity][batch][unit] bf16; rows 8-15 stay 0
    __shared__ __align__(16) short h2f[2][16][40];
    __shared__ __align__(16) float lasth[16][36];        // [batch][unit] fp32

    // ---- zero h buffers (and pad rows of xfrag)
    {
        short* p1 = &h1f[0][0][0];
        short* p2 = &h2f[0][0][0];
        for (int i = tid; i < 2 * 16 * 40; i += 512) { p1[i] = 0; p2[i] = 0; }
        short* px = &xfrag[TT][0][0];
        for (int i = tid; i < 4 * 64; i += 512) px[i] = 0;
    }

    // ---- stage x into [t][batch][k] bf16
    {
        const int bg0 = blockIdx.x * BPB;
        for (int p = tid; p < BPB * TT; p += 512) {
            const int b = p >> 9;            // 0..7
            const int t = p & (TT - 1);
            const float* src = imu + ((size_t)(bg0 + b) * TT + t) * 6;
            float2 a0 = *(const float2*)(src);
            float2 a1 = *(const float2*)(src + 2);
            float2 a2 = *(const float2*)(src + 4);
            unsigned* dst = (unsigned*)&xfrag[t][b][0];
            dst[0] = (unsigned short)f2bf(a0.x) | ((unsigned)(unsigned short)f2bf(a0.y) << 16);
            dst[1] = (unsigned short)f2bf(a1.x) | ((unsigned)(unsigned short)f2bf(a1.y) << 16);
            dst[2] = (unsigned short)f2bf(a2.x) | ((unsigned)(unsigned short)f2bf(a2.y) << 16);
            dst[3] = 0u;
        }
    }

    // ---- A-fragments: rows = weight rows, unit-major gate order (natural K).
    const int t0 = pair * 2, t1 = t0 + 1;
    const int m  = col;
    const int G0 = (m & 3) * 32 + t0 * 4 + (m >> 2);
    const int G1 = (m & 3) * 32 + t1 * 4 + (m >> 2);
    const int u0 = pair * 8 + kg;        // tile0 unit of this lane
    const int u1 = u0 + 4;               // tile1 unit
    const int myunit = u0 + (colhi ? 4 : 0);   // owned unit after MERGE

    short8 A00, A01, A10, A11;           // [tile][x-or-first / h-or-second]
    f32x4 bias0, bias1;
    if (layer == 0) {
        #pragma unroll
        for (int j = 0; j < 8; ++j) {
            A00[j] = (kg == 0 && j < 6) ? f2bf(w_ih0[G0 * 6 + j]) : (short)0;
            A10[j] = (kg == 0 && j < 6) ? f2bf(w_ih0[G1 * 6 + j]) : (short)0;
            A01[j] = f2bf(w_hh0[G0 * 32 + kg * 8 + j]);
            A11[j] = f2bf(w_hh0[G1 * 32 + kg * 8 + j]);
        }
        #pragma unroll
        for (int r = 0; r < 4; ++r) {
            bias0[r] = b_ih0[r * 32 + u0] + b_hh0[r * 32 + u0];
            bias1[r] = b_ih0[r * 32 + u1] + b_hh0[r * 32 + u1];
        }
    } else {
        #pragma unroll
        for (int j = 0; j < 8; ++j) {
            A00[j] = f2bf(w_ih1[G0 * 32 + kg * 8 + j]);
            A10[j] = f2bf(w_ih1[G1 * 32 + kg * 8 + j]);
            A01[j] = f2bf(w_hh1[G0 * 32 + kg * 8 + j]);
            A11[j] = f2bf(w_hh1[G1 * 32 + kg * 8 + j]);
        }
        #pragma unroll
        for (int r = 0; r < 4; ++r) {
            bias0[r] = b_ih1[r * 32 + u0] + b_hh1[r * 32 + u0];
            bias1[r] = b_ih1[r * 32 + u1] + b_hh1[r * 32 + u1];
        }
    }

    float c = 0.f;                       // this lane's single cell state

    const int xb = l & 7;                // batch whose x this lane feeds
    const short8* h1r0  = (const short8*)&h1f[0][col][kg * 8];
    const short8* h1r1  = (const short8*)&h1f[1][col][kg * 8];
    const short8* h2r0  = (const short8*)&h2f[0][col][kg * 8];
    const short8* h2r1  = (const short8*)&h2f[1][col][kg * 8];

    __syncthreads();

    // ======== prologue: L1 gates(0) with h1=0; prime xacc (x(1)-partial) ========
    short8 xvE = (short8)0, xvO = (short8)0;  // x prefetch regs (even/odd phases)
    f32x4 xacc0 = bias0, xacc1 = bias1;       // x-partial for next step's gates
    if (layer == 0) {
        short8 xv = *(const short8*)&xfrag[0][xb][0];
        f32x4 a0 = __builtin_amdgcn_mfma_f32_16x16x32_bf16(A00, xv, bias0, 0, 0, 0);
        f32x4 a1 = __builtin_amdgcn_mfma_f32_16x16x32_bf16(A10, xv, bias1, 0, 0, 0);
        f32x4 mg;
        MERGE(mg, a0, a1, colhi);
        float h;
        ACT_UPDATE(mg, c, h);
        h1f[1][batch][myunit] = cvt_bf16(h);
        short8 xv1 = *(const short8*)&xfrag[1][xb][0];
        xacc0 = __builtin_amdgcn_mfma_f32_16x16x32_bf16(A00, xv1, bias0, 0, 0, 0);
        xacc1 = __builtin_amdgcn_mfma_f32_16x16x32_bf16(A10, xv1, bias1, 0, 0, 0);
        xvE = *(const short8*)&xfrag[2][xb][0];   // drains in barrier
    }
    __syncthreads();

    // ======== main loop: STEP(T) = L1 gates(T+1) || L2 gates(T) ========
    // L1 post-barrier chain: ds_read hv -> 2 MFMA -> merge -> ACT -> write.
    // x-partial for gates(T+2) computed PRE-barrier from x prefetched 2 phases ago.
#define STEP(T, H1R, H2R, WP, XVC, XVL)                                         \
    {                                                                           \
        if (layer == 0) {                                                       \
            short8 hv = *(H1R);                                                 \
            f32x4 a0 = __builtin_amdgcn_mfma_f32_16x16x32_bf16(A01, hv, xacc0, 0, 0, 0); \
            f32x4 a1 = __builtin_amdgcn_mfma_f32_16x16x32_bf16(A11, hv, xacc1, 0, 0, 0); \
            f32x4 mg;                                                           \
            MERGE(mg, a0, a1, colhi);                                           \
            float h;                                                            \
            ACT_UPDATE(mg, c, h);                                               \
            h1f[WP][batch][myunit] = cvt_bf16(h);                               \
            xacc0 = __builtin_amdgcn_mfma_f32_16x16x32_bf16(A00, XVC, bias0, 0, 0, 0); \
            xacc1 = __builtin_amdgcn_mfma_f32_16x16x32_bf16(A10, XVC, bias1, 0, 0, 0); \
            XVL = *(const short8*)&xfrag[(T) + 3][xb][0];                       \
        } else {                                                                \
            short8 av = *(H1R);                                                 \
            short8 bv = *(H2R);                                                 \
            f32x4 a0 = __builtin_amdgcn_mfma_f32_16x16x32_bf16(A00, av, bias0, 0, 0, 0); \
            f32x4 a1 = __builtin_amdgcn_mfma_f32_16x16x32_bf16(A10, av, bias1, 0, 0, 0); \
            a0 = __builtin_amdgcn_mfma_f32_16x16x32_bf16(A01, bv, a0, 0, 0, 0); \
            a1 = __builtin_amdgcn_mfma_f32_16x16x32_bf16(A11, bv, a1, 0, 0, 0); \
            f32x4 mg;                                                           \
            MERGE(mg, a0, a1, colhi);                                           \
            float h;                                                            \
            ACT_UPDATE(mg, c, h);                                               \
            h2f[WP][batch][myunit] = cvt_bf16(h);                               \
        }                                                                       \
        __syncthreads();                                                        \
    }

    #pragma unroll 1
    for (int t = 0; t < TT - 2; t += 2) {
        STEP(t,     h1r1, h2r1, 0, xvE, xvO)   // even T: read parity 1, write 0
        STEP(t + 1, h1r0, h2r0, 1, xvO, xvE)   // odd  T: read parity 0, write 1
    }
    STEP(TT - 2, h1r1, h2r1, 0, xvE, xvO)      // T=510 (touches pad rows only)

    // ======== epilogue: L2 gates(511) -> lasth (fp32) ========
    if (layer == 1) {
        short8 av = *h1r0;           // h1(511) at parity 0
        short8 bv = *h2r0;           // h2(510) at parity 0
        f32x4 a0 = __builtin_amdgcn_mfma_f32_16x16x32_bf16(A00, av, bias0, 0, 0, 0);
        f32x4 a1 = __builtin_amdgcn_mfma_f32_16x16x32_bf16(A10, av, bias1, 0, 0, 0);
        a0 = __builtin_amdgcn_mfma_f32_16x16x32_bf16(A01, bv, a0, 0, 0, 0);
        a1 = __builtin_amdgcn_mfma_f32_16x16x32_bf16(A11, bv, a1, 0, 0, 0);
        f32x4 mg;
        MERGE(mg, a0, a1, colhi);
        float h;
        ACT_UPDATE(mg, c, h);
        lasth[batch][myunit] = h;
    }
    __syncthreads();

    // ======== heads: 512 threads = 8 batches x 64 outputs ========
    {
        const int b = tid >> 6;            // 0..7 (wave-uniform)
        const int o = tid & 63;
        float accF = bf[o], accN = bn[o];
        const float4* wf4 = (const float4*)(wf + o * 32);
        const float4* wn4 = (const float4*)(wn + o * 32);
        const float4* hv4 = (const float4*)&lasth[b][0];
        #pragma unroll
        for (int k = 0; k < 8; ++k) {
            float4 h4 = hv4[k];
            float4 f4 = wf4[k];
            float4 n4 = wn4[k];
            accF += f4.x * h4.x + f4.y * h4.y + f4.z * h4.z + f4.w * h4.w;
            accN += n4.x * h4.x + n4.y * h4.y + n4.z * h4.z + n4.w * h4.w;
        }
        const size_t bg = (size_t)blockIdx.x * BPB + b;
        out[bg * OUTD + o] = accF;
        out[(size_t)2048 * OUTD + bg * OUTD + o] = __expf(accN);
    }
}

extern "C" void kernel_launch(void* const* d_in, const int* in_sizes, int n_in,
                              void* d_out, int out_size, void* d_ws, size_t ws_size,
                              hipStream_t stream) {
    const float* imu   = (const float*)d_in[0];
    const float* w_ih0 = (const float*)d_in[1];
    const float* w_hh0 = (const float*)d_in[2];
    const float* b_ih0 = (const float*)d_in[3];
    const float* b_hh0 = (const float*)d_in[4];
    const float* w_ih1 = (const float*)d_in[5];
    const float* w_hh1 = (const float*)d_in[6];
    const float* b_ih1 = (const float*)d_in[7];
    const float* b_hh1 = (const float*)d_in[8];
    const float* wf    = (const float*)d_in[9];
    const float* bf    = (const float*)d_in[10];
    const float* wn    = (const float*)d_in[11];
    const float* bn    = (const float*)d_in[12];
    float* out = (float*)d_out;

    lstm2_inlane_kernel<<<dim3(NBLK), dim3(512), 0, stream>>>(
        imu, w_ih0, w_hh0, b_ih0, b_hh0,
        w_ih1, w_hh1, b_ih1, b_hh1,
        wf, bf, wn, bn, out);
}